// Round 4
// baseline (311.611 us; speedup 1.0000x reference)
//
#include <hip/hip_runtime.h>

// CTC forward loss, MI355X. Log-domain alpha recursion (proven exact in R2)
// + LDS-staged emissions (R3's memory path): triple-buffered 64-row chunks
// via global_load_lds with counted vmcnt waits, 4-deep register ring of
// pre-scaled emission values. One wave per example, no barriers in the loop.
//
// Lane l owns lattice states 4l+1..4l+4; state 0 is the blank-only path
// (a0 += Eb), tracked uniformly in all lanes. Cross-lane dep = prev lane's
// top two states -> two __shfl_up per step.

static constexpr float LOG2E_F = 1.4426950408889634f;
static constexpr float LN2_F   = 0.6931471805599453f;
#define NEGF (-1.0e30f)

#if __has_builtin(__builtin_amdgcn_exp2f)
#define FEXP2(x) __builtin_amdgcn_exp2f(x)
#else
#define FEXP2(x) exp2f(x)
#endif
#if __has_builtin(__builtin_amdgcn_logf)
#define FLOG2(x) __builtin_amdgcn_logf(x)
#else
#define FLOG2(x) log2f(x)
#endif

typedef __attribute__((address_space(3))) uint32_t lds_u32_t;
typedef const __attribute__((address_space(1))) uint32_t glb_u32_t;

template <int T, int C, int L>
__global__ __launch_bounds__(64) void ctc_alpha_log(
    const float* __restrict__ pred,      // (B,T,C) log-probs
    const int*   __restrict__ targets,   // (B,L)
    const int*   __restrict__ pred_len,  // (B)
    const int*   __restrict__ tgt_len,   // (B)
    float*       __restrict__ per_ex)    // (B) loss / target_len
{
  constexpr int ROWS    = 64;            // rows per staged chunk
  constexpr int CHUNK_F = ROWS * C;      // 8192 floats = 32 KiB
  constexpr int NCH     = T / ROWS;      // 16
  constexpr int S       = 2 * L + 1;     // 257

  __shared__ float emis[3 * CHUNK_F];    // 96 KiB triple buffer
  __shared__ float afin[S];              // final-alpha gather (outside loop)

  const int b = blockIdx.x;
  const int l = threadIdx.x;             // lane 0..63

  const float* __restrict__ prow = pred + (size_t)b * T * C;
  const int plen = pred_len[b];
  int tl = tgt_len[b]; if (tl < 1) tl = 1; if (tl > L) tl = L;

  // time-invariant per-lane label columns + skip flags
  const int cc1 = targets[b * L + 2 * l];          // state 4l+1
  const int cc3 = targets[b * L + 2 * l + 1];      // state 4l+3
  const bool skip1 = (l == 0) ? false : (cc1 != targets[b * L + 2 * l - 1]);
  const bool skip3 = (cc3 != cc1);

  // staging: chunk c (rows 64c..64c+63) -> buffer c%3, 32 x 1 KiB loads
  auto stage = [&](int c) {
    const float* src0 = prow + (size_t)c * CHUNK_F + (l << 2);
    float* dst0 = &emis[(c % 3) * CHUNK_F];
#pragma unroll
    for (int i = 0; i < 32; ++i) {
      __builtin_amdgcn_global_load_lds((glb_u32_t*)(src0 + (i << 8)),
                                       (lds_u32_t*)(dst0 + (i << 8)),
                                       16, 0, 0);
    }
  };

  stage(0); stage(1);
  asm volatile("s_waitcnt vmcnt(32)" ::: "memory");  // chunk 0 resident

  // t = 0 init (base-2 log space)
  float a0 = emis[0] * LOG2E_F;                      // state 0
  float x1 = (l == 0) ? emis[cc1] * LOG2E_F : NEGF;  // state 4l+1
  float x2 = NEGF, x3 = NEGF, x4 = NEGF;

  const int tmax = plen < T ? plen : T;              // steps t = 1..tmax-1

  auto step = [&](float Eb, float E1, float E3) {    // E* pre-scaled by log2e
    float P4 = __shfl_up(x4, 1);                     // prev lane state 4l
    float P3 = __shfl_up(x3, 1);                     // prev lane state 4l-1
    if (l == 0) { P4 = a0; P3 = NEGF; }
    const float s1 = skip1 ? P3 : NEGF;
    const float m1 = fmaxf(x1, fmaxf(P4, s1));
    const float n1 = m1 + FLOG2(FEXP2(x1 - m1) + FEXP2(P4 - m1) + FEXP2(s1 - m1)) + E1;
    const float m2 = fmaxf(x2, x1);
    const float n2 = m2 + FLOG2(FEXP2(x2 - m2) + FEXP2(x1 - m2)) + Eb;
    const float s3 = skip3 ? x1 : NEGF;
    const float m3 = fmaxf(x3, fmaxf(x2, s3));
    const float n3 = m3 + FLOG2(FEXP2(x3 - m3) + FEXP2(x2 - m3) + FEXP2(s3 - m3)) + E3;
    const float m4 = fmaxf(x4, x3);
    const float n4 = m4 + FLOG2(FEXP2(x4 - m4) + FEXP2(x3 - m4)) + Eb;
    a0 += Eb;
    x1 = n1; x2 = n2; x3 = n3; x4 = n4;
  };

  // 4-deep ring of PRE-SCALED emissions (scaling off the dependency chain)
  float reb[4], re1[4], re3[4];
  auto refill = [&](int rf, int j) {
    const int rb = ((rf >> 6) % 3) * CHUNK_F + (rf & 63) * C;
    reb[j] = emis[rb]       * LOG2E_F;
    re1[j] = emis[rb + cc1] * LOG2E_F;
    re3[j] = emis[rb + cc3] * LOG2E_F;
  };

  // steps 1..3 directly from resident chunk 0
#pragma unroll
  for (int t = 1; t <= 3; ++t) {
    if (t < tmax) {
      const int rb = t * C;
      step(emis[rb] * LOG2E_F, emis[rb + cc1] * LOG2E_F, emis[rb + cc3] * LOG2E_F);
    }
  }
  refill(4, 0); refill(5, 1); refill(6, 2); refill(7, 3);

  for (int c = 0; c < NCH; ++c) {
    if (c + 2 < NCH) stage(c + 2);
    // chunk c+1 must be resident (refills reach 4 rows past chunk c's end)
    if (c <= NCH - 3) asm volatile("s_waitcnt vmcnt(32)" ::: "memory");
    else              asm volatile("s_waitcnt vmcnt(0)"  ::: "memory");
    const int tq0 = (c == 0) ? 4 : c * ROWS;
    const int tqe = c * ROWS + (ROWS - 4);
    for (int tq = tq0; tq <= tqe; tq += 4) {
      if (tq + 3 < tmax) {
#pragma unroll
        for (int j = 0; j < 4; ++j) {
          const float Eb = reb[j], E1 = re1[j], E3 = re3[j];
          const int rf = tq + j + 4;
          if (rf < T) refill(rf, j);
          step(Eb, E1, E3);
        }
      } else {
#pragma unroll
        for (int j = 0; j < 4; ++j)
          if (tq + j < tmax) step(reb[j], re1[j], re3[j]);
      }
    }
  }

  // readout: per_ex = -logaddexp(alpha[2tl-1], alpha[2tl]) / tl (natural log)
  afin[4 * l + 1] = x1;
  afin[4 * l + 2] = x2;
  afin[4 * l + 3] = x3;
  afin[4 * l + 4] = x4;
  if (l == 0) afin[0] = a0;
  __syncthreads();
  if (l == 0) {
    const float l1 = afin[2 * tl - 1];
    const float l2 = afin[2 * tl];
    const float mm = fmaxf(l1, l2);
    const float ls = mm + FLOG2(FEXP2(l1 - mm) + FEXP2(l2 - mm));
    float per = -(ls * LN2_F);
    if (!(per < 1e29f)) per = 0.0f;                  // zero_infinity (inf/NaN)
    else if (per > 1e29f) per = 0.0f;
    per_ex[b] = per / (float)tl;
  }
}

__global__ void ctc_reduce_kernel(const float* __restrict__ per_ex,
                                  float* __restrict__ out, int B)
{
  const int l = threadIdx.x;  // one wave
  float v = 0.0f;
  for (int i = l; i < B; i += 64) v += per_ex[i];
#pragma unroll
  for (int off = 32; off > 0; off >>= 1) v += __shfl_down(v, off);
  if (l == 0) out[0] = v / (float)B;
}

extern "C" void kernel_launch(void* const* d_in, const int* in_sizes, int n_in,
                              void* d_out, int out_size, void* d_ws, size_t ws_size,
                              hipStream_t stream)
{
  const float* pred    = (const float*)d_in[0];
  const int*   targets = (const int*)d_in[1];
  const int*   plen    = (const int*)d_in[2];
  const int*   tlen    = (const int*)d_in[3];
  float*       out     = (float*)d_out;
  float*       ws      = (float*)d_ws;  // B floats scratch

  constexpr int B = 128, T = 1024, C = 128, L = 128;

  hipLaunchKernelGGL((ctc_alpha_log<T, C, L>), dim3(B), dim3(64), 0, stream,
                     pred, targets, plen, tlen, ws);
  hipLaunchKernelGGL(ctc_reduce_kernel, dim3(1), dim3(64), 0, stream,
                     ws, out, B);
}

// Round 5
// 218.210 us; speedup vs baseline: 1.4280x; 1.4280x over previous
//
#include <hip/hip_runtime.h>

// CTC forward loss, MI355X. Log-domain alpha recursion, one wave/example.
// R5: cross-lane via DPP wave_shr:1 (pure VALU, no LDS pipe); emissions
// staged to LDS (global_load_lds, triple-buffered 64-row chunks, counted
// vmcnt) and consumed through a 2-group (8-step) named register ring so the
// only lgkm dependency is one counted wait per 8 steps. lse2 uses the
// 1+exp2(-|d|) form (2 trans); lse3 uses max3 + 3 exp2 + log2.
//
// Lane l owns states 4l+1..4l+4; state 0 is the blank-only path a0 (uniform
// in all lanes). No barriers in the time loop.

static constexpr float LOG2E_F = 1.4426950408889634f;
static constexpr float LN2_F   = 0.6931471805599453f;
#define NEGF (-1.0e30f)

#if __has_builtin(__builtin_amdgcn_exp2f)
#define FEXP2(x) __builtin_amdgcn_exp2f(x)
#else
#define FEXP2(x) exp2f(x)
#endif
#if __has_builtin(__builtin_amdgcn_logf)
#define FLOG2(x) __builtin_amdgcn_logf(x)
#else
#define FLOG2(x) log2f(x)
#endif

typedef __attribute__((address_space(3))) uint32_t lds_u32_t;
typedef const __attribute__((address_space(1))) uint32_t glb_u32_t;

// Whole-wave shift right by one lane (gfx9 DPP wave_shr:1 = 0x138).
// Lane 0 receives `fill` (DPP old-operand, bound_ctrl=0 preserves old).
__device__ __forceinline__ float dpp_shr1(float src, float fill) {
  return __int_as_float(__builtin_amdgcn_update_dpp(
      __float_as_int(fill), __float_as_int(src), 0x138, 0xF, 0xF, false));
}

template <int T, int C, int L>
__global__ __launch_bounds__(64) void ctc_alpha_dpp(
    const float* __restrict__ pred,      // (B,T,C) log-probs
    const int*   __restrict__ targets,   // (B,L)
    const int*   __restrict__ pred_len,  // (B)
    const int*   __restrict__ tgt_len,   // (B)
    float*       __restrict__ per_ex)    // (B) loss / target_len
{
  constexpr int ROWS    = 64;
  constexpr int CHUNK_F = ROWS * C;      // 8192 floats = 32 KiB
  constexpr int NCH     = T / ROWS;      // 16
  constexpr int S       = 2 * L + 1;     // 257

  __shared__ float emis[3 * CHUNK_F];    // 96 KiB triple buffer
  __shared__ float afin[S];

  const int b = blockIdx.x;
  const int l = threadIdx.x;

  const float* __restrict__ prow = pred + (size_t)b * T * C;
  const int plen = pred_len[b];
  int tl = tgt_len[b]; if (tl < 1) tl = 1; if (tl > L) tl = L;

  const int cc1 = targets[b * L + 2 * l];          // state 4l+1 label
  const int cc3 = targets[b * L + 2 * l + 1];      // state 4l+3 label
  const bool skip1 = (l == 0) ? false : (cc1 != targets[b * L + 2 * l - 1]);
  const bool skip3 = (cc3 != cc1);

  auto stage = [&](int c) {
    const float* src0 = prow + (size_t)c * CHUNK_F + (l << 2);
    float* dst0 = &emis[(c % 3) * CHUNK_F];
#pragma unroll
    for (int i = 0; i < 32; ++i) {
      __builtin_amdgcn_global_load_lds((glb_u32_t*)(src0 + (i << 8)),
                                       (lds_u32_t*)(dst0 + (i << 8)),
                                       16, 0, 0);
    }
  };

  stage(0); stage(1);
  asm volatile("s_waitcnt vmcnt(32)" ::: "memory");  // chunk 0 resident

  float a0 = emis[0] * LOG2E_F;                      // state 0 (uniform)
  float x1 = (l == 0) ? emis[cc1] * LOG2E_F : NEGF;
  float x2 = NEGF, x3 = NEGF, x4 = NEGF;

  const int tmax = plen < T ? plen : T;              // steps 1..tmax-1

  auto step = [&](float rEb, float rE1, float rE3) {
    const float Eb = rEb * LOG2E_F;
    const float E1 = rE1 * LOG2E_F;
    const float E3 = rE3 * LOG2E_F;
    const float P4 = dpp_shr1(x4, a0);               // prev lane state 4l
    const float P3 = dpp_shr1(x3, NEGF);             // prev lane state 4l-1
    // state 4l+1 (odd): lse3(x1, P4, skip1 ? P3)
    const float s1 = skip1 ? P3 : NEGF;
    const float m1 = fmaxf(fmaxf(x1, P4), s1);
    const float n1 = m1 + FLOG2(FEXP2(x1 - m1) + FEXP2(P4 - m1) + FEXP2(s1 - m1)) + E1;
    // state 4l+2 (blank): lse2(x2, x1) = max + log2(1 + 2^-|d|)
    const float m2 = fmaxf(x2, x1);
    const float n2 = m2 + FLOG2(1.0f + FEXP2(-fabsf(x2 - x1))) + Eb;
    // state 4l+3 (odd): lse3(x3, x2, skip3 ? x1)
    const float s3 = skip3 ? x1 : NEGF;
    const float m3 = fmaxf(fmaxf(x3, x2), s3);
    const float n3 = m3 + FLOG2(FEXP2(x3 - m3) + FEXP2(x2 - m3) + FEXP2(s3 - m3)) + E3;
    // state 4l+4 (blank): lse2(x4, x3)
    const float m4 = fmaxf(x4, x3);
    const float n4 = m4 + FLOG2(1.0f + FEXP2(-fabsf(x4 - x3))) + Eb;
    a0 += Eb;
    x1 = n1; x2 = n2; x3 = n3; x4 = n4;
  };

  // load one 8-row group (raw values) into named register arrays
  auto loadg = [&](float (&gb)[8], float (&g1)[8], float (&g3)[8], int r0) {
#pragma unroll
    for (int j = 0; j < 8; ++j) {
      int rr = r0 + j; if (rr > T - 1) rr = T - 1;
      const int rb = ((rr >> 6) % 3) * CHUNK_F + (rr & 63) * C;
      gb[j] = emis[rb];
      g1[j] = emis[rb + cc1];
      g3[j] = emis[rb + cc3];
    }
  };

  // prologue: steps 1..7 straight from resident chunk 0
#pragma unroll
  for (int t = 1; t < 8; ++t) {
    if (t < tmax) {
      const int rb = t * C;
      step(emis[rb], emis[rb + cc1], emis[rb + cc3]);
    }
  }

  float Ab[8], A1[8], A3[8], Bb[8], B1[8], B3[8];
  loadg(Ab, A1, A3, 8);

  // main loop: 16 steps per iteration; group B loads overlap group A compute
  for (int t0 = 8; t0 + 16 <= T; t0 += 16) {
    if ((t0 & 63) == 8) {                            // entering chunk c
      const int c = t0 >> 6;
      if (c + 2 < NCH) {
        stage(c + 2);
        asm volatile("s_waitcnt vmcnt(32)" ::: "memory");  // c+1 resident
      } else {
        asm volatile("s_waitcnt vmcnt(0)" ::: "memory");
      }
    }
    loadg(Bb, B1, B3, t0 + 8);
    if (t0 + 16 <= tmax) {
#pragma unroll
      for (int j = 0; j < 8; ++j) step(Ab[j], A1[j], A3[j]);
      loadg(Ab, A1, A3, t0 + 16);
#pragma unroll
      for (int j = 0; j < 8; ++j) step(Bb[j], B1[j], B3[j]);
    } else {                                         // frozen-tail path
#pragma unroll
      for (int j = 0; j < 8; ++j)
        if (t0 + j < tmax) step(Ab[j], A1[j], A3[j]);
      loadg(Ab, A1, A3, t0 + 16);
#pragma unroll
      for (int j = 0; j < 8; ++j)
        if (t0 + 8 + j < tmax) step(Bb[j], B1[j], B3[j]);
    }
  }

  // readout: per_ex = -logaddexp(alpha[2tl-1], alpha[2tl]) / tl
  afin[4 * l + 1] = x1;
  afin[4 * l + 2] = x2;
  afin[4 * l + 3] = x3;
  afin[4 * l + 4] = x4;
  if (l == 0) afin[0] = a0;
  __syncthreads();
  if (l == 0) {
    const float l1 = afin[2 * tl - 1];
    const float l2 = afin[2 * tl];
    const float mm = fmaxf(l1, l2);
    const float ls = mm + FLOG2(FEXP2(l1 - mm) + FEXP2(l2 - mm));
    float per = -(ls * LN2_F);
    if (!(per < 1e29f)) per = 0.0f;                  // zero_infinity
    per_ex[b] = per / (float)tl;
  }
}

__global__ void ctc_reduce_kernel(const float* __restrict__ per_ex,
                                  float* __restrict__ out, int B)
{
  const int l = threadIdx.x;
  float v = 0.0f;
  for (int i = l; i < B; i += 64) v += per_ex[i];
#pragma unroll
  for (int off = 32; off > 0; off >>= 1) v += __shfl_down(v, off);
  if (l == 0) out[0] = v / (float)B;
}

extern "C" void kernel_launch(void* const* d_in, const int* in_sizes, int n_in,
                              void* d_out, int out_size, void* d_ws, size_t ws_size,
                              hipStream_t stream)
{
  const float* pred    = (const float*)d_in[0];
  const int*   targets = (const int*)d_in[1];
  const int*   plen    = (const int*)d_in[2];
  const int*   tlen    = (const int*)d_in[3];
  float*       out     = (float*)d_out;
  float*       ws      = (float*)d_ws;

  constexpr int B = 128, T = 1024, C = 128, L = 128;

  hipLaunchKernelGGL((ctc_alpha_dpp<T, C, L>), dim3(B), dim3(64), 0, stream,
                     pred, targets, plen, tlen, ws);
  hipLaunchKernelGGL(ctc_reduce_kernel, dim3(1), dim3(64), 0, stream,
                     ws, out, B);
}

// Round 7
// 193.687 us; speedup vs baseline: 1.6088x; 1.1266x over previous
//
#include <hip/hip_runtime.h>

// CTC forward loss, MI355X. Linear-domain alpha recursion with PER-LANE
// power-of-2 renorm (every 8 steps) + per-lane int exponent E; cross-lane
// flow rescaled by 2^(E_prev - E); dead lanes adopt left neighbor's E per
// step (int DPP) so the lattice frontier never sees a large dE.
// Emissions staged to LDS (global_load_lds triple buffer, counted vmcnt),
// consumed via 8-step named register groups; exp2 happens at refill time,
// OFF the recurrence chain. Recurrence itself is pure VALU (no trans).
// One wave per example; cross-lane via DPP wave_shr:1; no barriers in loop.
// (Resubmission of R6 — previous round failed on container infra, no signal.)

static constexpr float LOG2E_F = 1.4426950408889634f;
static constexpr float LN2_F   = 0.6931471805599453f;

#if __has_builtin(__builtin_amdgcn_exp2f)
#define FEXP2(x) __builtin_amdgcn_exp2f(x)
#else
#define FEXP2(x) exp2f(x)
#endif
#if __has_builtin(__builtin_amdgcn_logf)
#define FLOG2(x) __builtin_amdgcn_logf(x)
#else
#define FLOG2(x) log2f(x)
#endif

typedef __attribute__((address_space(3))) uint32_t lds_u32_t;
typedef const __attribute__((address_space(1))) uint32_t glb_u32_t;

__device__ __forceinline__ float dpp_shr1(float src, float fill) {
  return __int_as_float(__builtin_amdgcn_update_dpp(
      __float_as_int(fill), __float_as_int(src), 0x138, 0xF, 0xF, false));
}
__device__ __forceinline__ int dpp_shr1_i(int src, int fill) {
  return __builtin_amdgcn_update_dpp(fill, src, 0x138, 0xF, 0xF, false);
}

template <int T, int C, int L>
__global__ __launch_bounds__(64) void ctc_alpha_lin2(
    const float* __restrict__ pred,      // (B,T,C) log-probs
    const int*   __restrict__ targets,   // (B,L)
    const int*   __restrict__ pred_len,  // (B)
    const int*   __restrict__ tgt_len,   // (B)
    float*       __restrict__ per_ex)    // (B) loss / target_len
{
  constexpr int ROWS    = 64;
  constexpr int CHUNK_F = ROWS * C;      // 8192 floats = 32 KiB
  constexpr int NCH     = T / ROWS;      // 16
  constexpr int S       = 2 * L + 1;     // 257

  __shared__ float emis[3 * CHUNK_F];    // 96 KiB triple buffer
  __shared__ float afin[S];

  const int b = blockIdx.x;
  const int l = threadIdx.x;

  const float* __restrict__ prow = pred + (size_t)b * T * C;
  const int plen = pred_len[b];
  int tl = tgt_len[b]; if (tl < 1) tl = 1; if (tl > L) tl = L;

  const int cc1 = targets[b * L + 2 * l];          // state 4l+1 label
  const int cc3 = targets[b * L + 2 * l + 1];      // state 4l+3 label
  const float k1 = (l == 0) ? 0.0f
                  : ((cc1 != targets[b * L + 2 * l - 1]) ? 1.0f : 0.0f);
  const float k3 = (cc3 != cc1) ? 1.0f : 0.0f;

  auto stage = [&](int c) {
    const float* src0 = prow + (size_t)c * CHUNK_F + (l << 2);
    float* dst0 = &emis[(c % 3) * CHUNK_F];
#pragma unroll
    for (int i = 0; i < 32; ++i) {
      __builtin_amdgcn_global_load_lds((glb_u32_t*)(src0 + (i << 8)),
                                       (lds_u32_t*)(dst0 + (i << 8)),
                                       16, 0, 0);
    }
  };

  stage(0); stage(1);
  asm volatile("s_waitcnt vmcnt(32)" ::: "memory");  // chunk 0 resident

  // state: linear alpha (lane frame = true_alpha * 2^-E), int exponent E
  float a0 = FEXP2(emis[0] * LOG2E_F);               // state 0 (lane-0 frame)
  float x1 = (l == 0) ? FEXP2(emis[cc1] * LOG2E_F) : 0.0f;
  float x2 = 0.0f, x3 = 0.0f, x4 = 0.0f;
  int   E  = 0;

  const int tmax = plen < T ? plen : T;              // steps 1..tmax-1

  auto step = [&](float Eb, float E1, float E3) {    // LINEAR emission factors
    const int Eprev = dpp_shr1_i(E, E);              // lane0: own E -> dE=0
    const uint32_t orx = __float_as_uint(x1) | __float_as_uint(x2) |
                         __float_as_uint(x3) | __float_as_uint(x4);
    if (orx == 0u) E = Eprev;                        // dead lane adopts E
    int dE = Eprev - E;
    dE = dE < -126 ? -126 : (dE > 126 ? 126 : dE);
    const float sc = __int_as_float((dE + 127) << 23);   // exact 2^dE
    const float P4 = dpp_shr1(x4, a0) * sc;          // prev-lane state 4l
    const float P3 = dpp_shr1(x3, x3) * sc;          // prev-lane state 4l-1
    const float t1 = fmaf(k1, P3, x1 + P4);
    const float t2 = x2 + x1;
    const float t3 = fmaf(k3, x1, x3 + x2);
    const float t4 = x4 + x3;
    x1 = t1 * E1; x2 = t2 * Eb; x3 = t3 * E3; x4 = t4 * Eb;
    a0 *= Eb;
  };

  auto renorm = [&]() {                              // exact pow2 rescale
    const float m = fmaxf(fmaxf(fmaxf(x1, x2), fmaxf(x3, x4)), a0);
    int ebi = (int)((__float_as_uint(m) >> 23) & 0xffu);
    if (ebi == 0) ebi = 126;                         // dead/denorm: no-op
    const float sc = __uint_as_float((uint32_t)(253 - ebi) << 23);
    x1 *= sc; x2 *= sc; x3 *= sc; x4 *= sc; a0 *= sc;
    E += ebi - 126;
  };

  // load one 8-row group and convert to LINEAR factors (exp2 off-chain)
  auto loadg = [&](float (&gb)[8], float (&g1)[8], float (&g3)[8], int r0) {
#pragma unroll
    for (int j = 0; j < 8; ++j) {
      int rr = r0 + j; if (rr > T - 1) rr = T - 1;
      const int rb = ((rr >> 6) % 3) * CHUNK_F + (rr & 63) * C;
      gb[j] = FEXP2(emis[rb]       * LOG2E_F);
      g1[j] = FEXP2(emis[rb + cc1] * LOG2E_F);
      g3[j] = FEXP2(emis[rb + cc3] * LOG2E_F);
    }
  };

  // prologue: steps 1..15 from resident chunk 0 (renorm mid-way for range)
#pragma unroll
  for (int t = 1; t < 16; ++t) {
    if (t == 8) renorm();
    if (t < tmax) {
      const int rb = t * C;
      step(FEXP2(emis[rb]       * LOG2E_F),
           FEXP2(emis[rb + cc1] * LOG2E_F),
           FEXP2(emis[rb + cc3] * LOG2E_F));
    }
  }

  float Ab[8], A1[8], A3[8], Bb[8], B1[8], B3[8];
  loadg(Ab, A1, A3, 16);

  // main loop: 16 steps/iter covering t = 16 .. 1023 (63 iterations)
  for (int t0 = 16; t0 + 16 <= T; t0 += 16) {
    if ((t0 & 63) == 16) {                           // entering chunk c
      const int c = t0 >> 6;
      if (c + 2 < NCH) {
        stage(c + 2);
        asm volatile("s_waitcnt vmcnt(32)" ::: "memory");  // c+1 resident
      } else {
        asm volatile("s_waitcnt vmcnt(0)" ::: "memory");
      }
    }
    loadg(Bb, B1, B3, t0 + 8);
    renorm();
    if (t0 + 16 <= tmax) {
#pragma unroll
      for (int j = 0; j < 8; ++j) step(Ab[j], A1[j], A3[j]);
      loadg(Ab, A1, A3, t0 + 16);
      renorm();
#pragma unroll
      for (int j = 0; j < 8; ++j) step(Bb[j], B1[j], B3[j]);
    } else {                                         // frozen-tail path
#pragma unroll
      for (int j = 0; j < 8; ++j)
        if (t0 + j < tmax) step(Ab[j], A1[j], A3[j]);
      loadg(Ab, A1, A3, t0 + 16);
      renorm();
#pragma unroll
      for (int j = 0; j < 8; ++j)
        if (t0 + 8 + j < tmax) step(Bb[j], B1[j], B3[j]);
    }
  }

  // readout: log2(alpha) = log2(x) + E per state; then lse2 in log2 domain
  const float fE = (float)E;
  afin[4 * l + 1] = FLOG2(x1) + fE;
  afin[4 * l + 2] = FLOG2(x2) + fE;
  afin[4 * l + 3] = FLOG2(x3) + fE;
  afin[4 * l + 4] = FLOG2(x4) + fE;
  if (l == 0) afin[0] = FLOG2(a0) + fE;
  __syncthreads();
  if (l == 0) {
    const float l1 = afin[2 * tl - 1];
    const float l2 = afin[2 * tl];
    const float mm = fmaxf(l1, l2);
    const float ls = mm + FLOG2(FEXP2(l1 - mm) + FEXP2(l2 - mm));
    float per = -(ls * LN2_F);
    if (!(per < 1e29f)) per = 0.0f;                  // zero_infinity (inf/NaN)
    per_ex[b] = per / (float)tl;
  }
}

__global__ void ctc_reduce_kernel(const float* __restrict__ per_ex,
                                  float* __restrict__ out, int B)
{
  const int l = threadIdx.x;
  float v = 0.0f;
  for (int i = l; i < B; i += 64) v += per_ex[i];
#pragma unroll
  for (int off = 32; off > 0; off >>= 1) v += __shfl_down(v, off);
  if (l == 0) out[0] = v / (float)B;
}

extern "C" void kernel_launch(void* const* d_in, const int* in_sizes, int n_in,
                              void* d_out, int out_size, void* d_ws, size_t ws_size,
                              hipStream_t stream)
{
  const float* pred    = (const float*)d_in[0];
  const int*   targets = (const int*)d_in[1];
  const int*   plen    = (const int*)d_in[2];
  const int*   tlen    = (const int*)d_in[3];
  float*       out     = (float*)d_out;
  float*       ws      = (float*)d_ws;

  constexpr int B = 128, T = 1024, C = 128, L = 128;

  hipLaunchKernelGGL((ctc_alpha_lin2<T, C, L>), dim3(B), dim3(64), 0, stream,
                     pred, targets, plen, tlen, ws);
  hipLaunchKernelGGL(ctc_reduce_kernel, dim3(1), dim3(64), 0, stream,
                     ws, out, B);
}